// Round 1
// baseline (138.838 us; speedup 1.0000x reference)
//
#include <hip/hip_runtime.h>

#define VOCAB 64
#define HID 64
#define SEQL 48
#define MSLOTS 8
#define BLKT 256

// ws layout (floats): [0,4096) Wq = embed @ W1[:, :64].T
//                     [4096,8192) Wm = embed @ W1[:, 64:].T
//                     [8192,8200) ww = w_m / count
__global__ void ebb_prep(const float* __restrict__ embed,
                         const float* __restrict__ W1,
                         const float* __restrict__ log_stab,
                         float* __restrict__ ws) {
    int t = blockIdx.x;            // token 0..63
    int tid = threadIdx.x;         // 0..127
    int table = tid >> 6;          // 0 -> Wq (W1[:, :64]), 1 -> Wm (W1[:, 64:])
    int col = tid & 63;            // output hidden index j
    const float* erow = embed + t * HID;
    const float* wrow = W1 + col * (2 * HID) + table * HID;
    float acc = 0.f;
#pragma unroll
    for (int k = 0; k < HID; ++k) acc = fmaf(erow[k], wrow[k], acc);
    ws[table * (VOCAB * HID) + t * HID + col] = acc;

    if (blockIdx.x == 0 && tid < MSLOTS) {
        float S = expf(log_stab[0]);
        float cnt = 0.f;
        for (int m = 0; m < MSLOTS; ++m) {
            float age = (float)(MSLOTS - 1 - m);
            cnt += (expf(-age / S) >= 0.05f) ? 1.f : 0.f;
        }
        cnt = fmaxf(cnt, 1.f);
        float age = (float)(MSLOTS - 1 - tid);
        float keep = (expf(-age / S) >= 0.05f) ? 1.f : 0.f;
        float w = expf(-age * (age + 1.f) / (2.f * S)) * keep;
        ws[2 * VOCAB * HID + tid] = w / cnt;
    }
}

__global__ __launch_bounds__(BLKT, 2)
void ebb_main(const int* __restrict__ seqs, const int* __restrict__ qtok,
              const float* __restrict__ ws, const float* __restrict__ W2,
              const float* __restrict__ b1, const float* __restrict__ b2,
              float* __restrict__ out, int B) {
    __shared__ float sWq[VOCAB][HID + 1];   // pad 65: gather bank = (tok+j)%32
    __shared__ float sWm[VOCAB][HID + 1];
    __shared__ float sW2[VOCAB * HID];      // uniform broadcast reads, no pad
    __shared__ float sB1[HID], sB2[HID], sWW[MSLOTS];

    int tid = threadIdx.x;
    for (int i = tid; i < VOCAB * HID; i += BLKT) {
        int r = i >> 6, c = i & 63;
        sWq[r][c] = ws[i];
        sWm[r][c] = ws[VOCAB * HID + i];
        sW2[i] = W2[i];
    }
    if (tid < HID) { sB1[tid] = b1[tid]; sB2[tid] = b2[tid]; }
    if (tid < MSLOTS) sWW[tid] = ws[2 * VOCAB * HID + tid];
    __syncthreads();

    int row = blockIdx.x * BLKT + tid;
    if (row >= B) return;

    const int* srow = seqs + (size_t)row * SEQL + (SEQL - 1 - MSLOTS);
    int qt = qtok[row];

    float h[HID];
    {
        const float* wq = &sWq[qt][0];
#pragma unroll
        for (int j = 0; j < HID; ++j) h[j] = sB1[j] + wq[j];
    }
#pragma unroll 1
    for (int m = 0; m < MSLOTS; ++m) {
        int t = srow[m];
        float wwm = sWW[m];
        const float* wm = &sWm[t][0];
#pragma unroll
        for (int j = 0; j < HID; ++j) h[j] = fmaf(wwm, wm[j], h[j]);
    }
#pragma unroll
    for (int j = 0; j < HID; ++j) h[j] = fmaxf(h[j], 0.f);

    float* orow = out + (size_t)row * VOCAB;
#pragma unroll 1
    for (int v0 = 0; v0 < VOCAB; v0 += 4) {
        float a0 = sB2[v0 + 0], a1 = sB2[v0 + 1], a2 = sB2[v0 + 2], a3 = sB2[v0 + 3];
        const float4* w0 = (const float4*)&sW2[(v0 + 0) * HID];
        const float4* w1 = (const float4*)&sW2[(v0 + 1) * HID];
        const float4* w2 = (const float4*)&sW2[(v0 + 2) * HID];
        const float4* w3 = (const float4*)&sW2[(v0 + 3) * HID];
#pragma unroll
        for (int j4 = 0; j4 < HID / 4; ++j4) {
            float4 x0 = w0[j4], x1 = w1[j4], x2 = w2[j4], x3 = w3[j4];
            float h0 = h[4 * j4 + 0], h1 = h[4 * j4 + 1], h2 = h[4 * j4 + 2], h3 = h[4 * j4 + 3];
            a0 = fmaf(h0, x0.x, a0); a0 = fmaf(h1, x0.y, a0); a0 = fmaf(h2, x0.z, a0); a0 = fmaf(h3, x0.w, a0);
            a1 = fmaf(h0, x1.x, a1); a1 = fmaf(h1, x1.y, a1); a1 = fmaf(h2, x1.z, a1); a1 = fmaf(h3, x1.w, a1);
            a2 = fmaf(h0, x2.x, a2); a2 = fmaf(h1, x2.y, a2); a2 = fmaf(h2, x2.z, a2); a2 = fmaf(h3, x2.w, a2);
            a3 = fmaf(h0, x3.x, a3); a3 = fmaf(h1, x3.y, a3); a3 = fmaf(h2, x3.z, a3); a3 = fmaf(h3, x3.w, a3);
        }
        float4 o; o.x = a0; o.y = a1; o.z = a2; o.w = a3;
        ((float4*)orow)[v0 >> 2] = o;
    }
}

extern "C" void kernel_launch(void* const* d_in, const int* in_sizes, int n_in,
                              void* d_out, int out_size, void* d_ws, size_t ws_size,
                              hipStream_t stream) {
    const int*   seqs     = (const int*)d_in[0];
    const int*   qtok     = (const int*)d_in[1];
    const float* embed    = (const float*)d_in[2];
    const float* W1       = (const float*)d_in[3];
    const float* b1       = (const float*)d_in[4];
    const float* W2       = (const float*)d_in[5];
    const float* b2       = (const float*)d_in[6];
    const float* log_stab = (const float*)d_in[7];
    float* out = (float*)d_out;
    float* ws  = (float*)d_ws;

    int B = in_sizes[1];

    ebb_prep<<<VOCAB, 2 * HID, 0, stream>>>(embed, W1, log_stab, ws);

    int nblk = (B + BLKT - 1) / BLKT;
    ebb_main<<<nblk, BLKT, 0, stream>>>(seqs, qtok, ws, W2, b1, b2, out, B);
}

// Round 3
// 135.442 us; speedup vs baseline: 1.0251x; 1.0251x over previous
//
#include <hip/hip_runtime.h>

#define VOCAB 64
#define HID 64
#define SEQL 48
#define MSLOTS 8
#define BLKT 256
#define PAD 4            // table row stride = 68 floats = 272 B (16B-aligned)

// ws layout (floats): [0,4096)    Wq = embed @ W1[:, :64].T + b1
//                     [4096,8192) Wm = embed @ W1[:, 64:].T
//                     [8192,8200) ww = w_m / count
__global__ void ebb_prep(const float* __restrict__ embed,
                         const float* __restrict__ W1,
                         const float* __restrict__ b1,
                         const float* __restrict__ log_stab,
                         float* __restrict__ ws) {
    int t = blockIdx.x;            // token 0..63
    int tid = threadIdx.x;         // 0..127
    int table = tid >> 6;          // 0 -> Wq (W1[:, :64]), 1 -> Wm (W1[:, 64:])
    int col = tid & 63;            // output hidden index j
    const float* erow = embed + t * HID;
    const float* wrow = W1 + col * (2 * HID) + table * HID;
    float acc = (table == 0) ? b1[col] : 0.f;   // fold b1 into Wq
#pragma unroll
    for (int k = 0; k < HID; ++k) acc = fmaf(erow[k], wrow[k], acc);
    ws[table * (VOCAB * HID) + t * HID + col] = acc;

    if (blockIdx.x == 0 && tid < MSLOTS) {
        float S = expf(log_stab[0]);
        float cnt = 0.f;
        for (int m = 0; m < MSLOTS; ++m) {
            float age = (float)(MSLOTS - 1 - m);
            cnt += (expf(-age / S) >= 0.05f) ? 1.f : 0.f;
        }
        cnt = fmaxf(cnt, 1.f);
        float age = (float)(MSLOTS - 1 - tid);
        float keep = (expf(-age / S) >= 0.05f) ? 1.f : 0.f;
        float w = expf(-age * (age + 1.f) / (2.f * S)) * keep;
        ws[2 * VOCAB * HID + tid] = w / cnt;
    }
}

__global__ __launch_bounds__(BLKT, 3)
void ebb_main(const int* __restrict__ seqs, const int* __restrict__ qtok,
              const float* __restrict__ ws, const float* __restrict__ W2,
              const float* __restrict__ b2,
              float* __restrict__ out, int B) {
    __shared__ float sWq[VOCAB][HID + PAD];   // 17408 B
    __shared__ float sWm[VOCAB][HID + PAD];   // 17408 B
    __shared__ float4 sOut[BLKT * 4];         // 16384 B write-staging

    int tid = threadIdx.x;
    for (int i = tid; i < VOCAB * HID; i += BLKT) {
        int r = i >> 6, c = i & 63;
        sWq[r][c] = ws[i];
        sWm[r][c] = ws[VOCAB * HID + i];
    }
    __syncthreads();

    long row = (long)blockIdx.x * BLKT + tid;   // B divisible by 256 (131072)
    const int* srow = seqs + row * SEQL;
    int qt = qtok[row];
    // memory tokens = seqs[row, 39..46]; bytes 156..187: dword + 2 aligned int4
    int t0 = srow[39];
    int4 ta = *(const int4*)(srow + 40);   // cols 40..43 (byte 160, aligned)
    int4 tb = *(const int4*)(srow + 44);   // cols 44..47 (byte 176, aligned; .w unused)
    int toks[MSLOTS] = {t0, ta.x, ta.y, ta.z, ta.w, tb.x, tb.y, tb.z};

    // ---- layer 1: h = relu(Wq[qt] + sum_m ww[m]*Wm[toks[m]]) (b1 folded) ----
    float h[HID];
    {
        const float4* wq = (const float4*)&sWq[qt][0];
#pragma unroll
        for (int j4 = 0; j4 < 16; ++j4) {
            float4 a = wq[j4];
            h[4 * j4 + 0] = a.x; h[4 * j4 + 1] = a.y;
            h[4 * j4 + 2] = a.z; h[4 * j4 + 3] = a.w;
        }
    }
#pragma unroll
    for (int m = 0; m < MSLOTS; ++m) {
        int t = toks[m];
        float wwm = ws[2 * VOCAB * HID + m];          // uniform -> s_load
        const float4* wm = (const float4*)&sWm[t][0];
#pragma unroll
        for (int j4 = 0; j4 < 16; ++j4) {
            float4 a = wm[j4];
            h[4 * j4 + 0] = fmaf(wwm, a.x, h[4 * j4 + 0]);
            h[4 * j4 + 1] = fmaf(wwm, a.y, h[4 * j4 + 1]);
            h[4 * j4 + 2] = fmaf(wwm, a.z, h[4 * j4 + 2]);
            h[4 * j4 + 3] = fmaf(wwm, a.w, h[4 * j4 + 3]);
        }
    }
#pragma unroll
    for (int j = 0; j < HID; ++j) h[j] = fmaxf(h[j], 0.f);

    // ---- layer 2: logits = h @ W2.T + b2, staged through LDS for ----
    // ---- full-cache-line coalesced writes                         ----
    const float4* W2v = (const float4*)W2;   // uniform -> s_load
    const float4* b2v = (const float4*)b2;
    int swz = (tid >> 1) & 3;
    long orow0 = (long)blockIdx.x * BLKT;
#pragma unroll 1
    for (int c = 0; c < 4; ++c) {            // 16 outputs per chunk
        for (int q = 0; q < 4; ++q) {        // 4 outputs per quad
            int v = c * 16 + q * 4;          // W2 rows v..v+3
            float4 bb = b2v[c * 4 + q];
            float a0 = bb.x, a1 = bb.y, a2 = bb.z, a3 = bb.w;
#pragma unroll
            for (int j4 = 0; j4 < 16; ++j4) {
                float4 x0 = W2v[(v + 0) * 16 + j4];
                float4 x1 = W2v[(v + 1) * 16 + j4];
                float4 x2 = W2v[(v + 2) * 16 + j4];
                float4 x3 = W2v[(v + 3) * 16 + j4];
                float h0 = h[4 * j4 + 0], h1 = h[4 * j4 + 1];
                float h2 = h[4 * j4 + 2], h3 = h[4 * j4 + 3];
                a0 = fmaf(h0, x0.x, a0); a0 = fmaf(h1, x0.y, a0);
                a0 = fmaf(h2, x0.z, a0); a0 = fmaf(h3, x0.w, a0);
                a1 = fmaf(h0, x1.x, a1); a1 = fmaf(h1, x1.y, a1);
                a1 = fmaf(h2, x1.z, a1); a1 = fmaf(h3, x1.w, a1);
                a2 = fmaf(h0, x2.x, a2); a2 = fmaf(h1, x2.y, a2);
                a2 = fmaf(h2, x2.z, a2); a2 = fmaf(h3, x2.w, a2);
                a3 = fmaf(h0, x3.x, a3); a3 = fmaf(h1, x3.y, a3);
                a3 = fmaf(h2, x3.z, a3); a3 = fmaf(h3, x3.w, a3);
            }
            sOut[tid * 4 + (q ^ swz)] = make_float4(a0, a1, a2, a3);
        }
        __syncthreads();
        // drain: every 4 consecutive lanes write one full 64B line
#pragma unroll
        for (int s = 0; s < 4; ++s) {
            int flat = s * BLKT + tid;
            int r = flat >> 2;               // row within block
            int q = flat & 3;                // quad within chunk
            float4 val = sOut[r * 4 + (q ^ ((r >> 1) & 3))];
            ((float4*)out)[(orow0 + r) * 16 + c * 4 + q] = val;
        }
        __syncthreads();
    }
}

extern "C" void kernel_launch(void* const* d_in, const int* in_sizes, int n_in,
                              void* d_out, int out_size, void* d_ws, size_t ws_size,
                              hipStream_t stream) {
    const int*   seqs     = (const int*)d_in[0];
    const int*   qtok     = (const int*)d_in[1];
    const float* embed    = (const float*)d_in[2];
    const float* W1       = (const float*)d_in[3];
    const float* b1       = (const float*)d_in[4];
    const float* W2       = (const float*)d_in[5];
    const float* b2       = (const float*)d_in[6];
    const float* log_stab = (const float*)d_in[7];
    float* out = (float*)d_out;
    float* ws  = (float*)d_ws;

    int B = in_sizes[1];

    ebb_prep<<<VOCAB, 2 * HID, 0, stream>>>(embed, W1, b1, log_stab, ws);

    int nblk = (B + BLKT - 1) / BLKT;
    ebb_main<<<nblk, BLKT, 0, stream>>>(seqs, qtok, ws, W2, b2, out, B);
}

// Round 6
// 126.790 us; speedup vs baseline: 1.0950x; 1.0682x over previous
//
#include <hip/hip_runtime.h>

#define VOCAB 64
#define HID 64
#define SEQL 48
#define MSLOTS 8
#define BLKT 256
#define STR 68   // padded LDS row stride in floats (272B, 16B-aligned)

// ws layout (floats): [0,4096)    Wq = embed @ W1[:, :64].T + b1
//                     [4096,8192) Wm = embed @ W1[:, 64:].T
//                     [8192,8200) ww = w_m / count
__global__ void ebb_prep(const float* __restrict__ embed,
                         const float* __restrict__ W1,
                         const float* __restrict__ b1,
                         const float* __restrict__ log_stab,
                         float* __restrict__ ws) {
    int t = blockIdx.x;            // token 0..63
    int tid = threadIdx.x;         // 0..127
    int table = tid >> 6;          // 0 -> Wq (W1[:, :64]), 1 -> Wm (W1[:, 64:])
    int col = tid & 63;            // output hidden index j
    const float* erow = embed + t * HID;
    const float* wrow = W1 + col * (2 * HID) + table * HID;
    float acc = (table == 0) ? b1[col] : 0.f;   // fold b1 into Wq
#pragma unroll
    for (int k = 0; k < HID; ++k) acc = fmaf(erow[k], wrow[k], acc);
    ws[table * (VOCAB * HID) + t * HID + col] = acc;

    if (blockIdx.x == 0 && tid < MSLOTS) {
        float S = expf(log_stab[0]);
        float cnt = 0.f;
        for (int m = 0; m < MSLOTS; ++m) {
            float age = (float)(MSLOTS - 1 - m);
            cnt += (expf(-age / S) >= 0.05f) ? 1.f : 0.f;
        }
        cnt = fmaxf(cnt, 1.f);
        float age = (float)(MSLOTS - 1 - tid);
        float keep = (expf(-age / S) >= 0.05f) ? 1.f : 0.f;
        float w = expf(-age * (age + 1.f) / (2.f * S)) * keep;
        ws[2 * VOCAB * HID + tid] = w / cnt;
    }
}

// Each thread owns output column (tid&63), holding W2[col][:] in 16 float4
// VGPRs for the whole kernel. Layer1 per-thread -> h[64] in VGPRs. Layer2:
// per 64-row chunk, owner wave dumps h into LDS; all 4 waves sweep rows with
// wave-uniform ds_read_b128 broadcasts of h + resident-W2 FMAs; each store
// instruction emits one full contiguous 256B output row.
__global__ __launch_bounds__(BLKT, 2)
void ebb_main(const int* __restrict__ seqs, const int* __restrict__ qtok,
              const float* __restrict__ ws, const float* __restrict__ W2,
              const float* __restrict__ b2,
              float* __restrict__ out) {
    __shared__ float sWq[VOCAB][STR];   // 17408 B
    __shared__ float sWm[VOCAB][STR];   // 17408 B
    __shared__ float sH[64][STR];       // 17408 B  (52.2 KB total)

    int tid  = threadIdx.x;
    int lane = tid & 63;
    int wv   = tid >> 6;

    // ---- stage gather tables ----
    for (int i = tid; i < VOCAB * HID; i += BLKT) {
        int r = i >> 6, c = i & 63;
        sWq[r][c] = ws[i];
        sWm[r][c] = ws[VOCAB * HID + i];
    }

    // ---- resident W2 row for this thread's output column (one-time) ----
    float4 w2r[16];
    {
        const float4* W2v = (const float4*)(W2 + lane * HID);
#pragma unroll
        for (int j4 = 0; j4 < 16; ++j4) w2r[j4] = W2v[j4];
    }
    float bb = b2[lane];

    // ---- this thread's row inputs ----
    int row = blockIdx.x * BLKT + tid;            // B divisible by 256
    const int* srow = seqs + (size_t)row * SEQL;
    int qt = qtok[row];
    int t0 = srow[39];
    int4 ta = *(const int4*)(srow + 40);
    int4 tb = *(const int4*)(srow + 44);
    int toks[MSLOTS] = {t0, ta.x, ta.y, ta.z, ta.w, tb.x, tb.y, tb.z};

    __syncthreads();   // tables ready

    // ---- layer 1: h = relu(Wq[qt] + sum_m ww[m]*Wm[toks[m]]) ----
    float h[HID];
    {
        const float4* wq = (const float4*)&sWq[qt][0];
#pragma unroll
        for (int j4 = 0; j4 < 16; ++j4) {
            float4 a = wq[j4];
            h[4 * j4 + 0] = a.x; h[4 * j4 + 1] = a.y;
            h[4 * j4 + 2] = a.z; h[4 * j4 + 3] = a.w;
        }
    }
#pragma unroll
    for (int m = 0; m < MSLOTS; ++m) {
        float wwm = ws[2 * VOCAB * HID + m];      // uniform -> s_load
        const float4* wm = (const float4*)&sWm[toks[m]][0];
#pragma unroll
        for (int j4 = 0; j4 < 16; ++j4) {
            float4 a = wm[j4];
            h[4 * j4 + 0] = fmaf(wwm, a.x, h[4 * j4 + 0]);
            h[4 * j4 + 1] = fmaf(wwm, a.y, h[4 * j4 + 1]);
            h[4 * j4 + 2] = fmaf(wwm, a.z, h[4 * j4 + 2]);
            h[4 * j4 + 3] = fmaf(wwm, a.w, h[4 * j4 + 3]);
        }
    }
#pragma unroll
    for (int j = 0; j < HID; ++j) h[j] = fmaxf(h[j], 0.f);

    // ---- layer 2: cooperative, 4 chunks of 64 rows ----
    size_t obase = (size_t)blockIdx.x * BLKT * HID;
#pragma unroll 1
    for (int c = 0; c < 4; ++c) {
        if (wv == c) {                    // owner wave dumps its h rows
            float4* dst = (float4*)&sH[lane][0];
#pragma unroll
            for (int j4 = 0; j4 < 16; ++j4)
                dst[j4] = make_float4(h[4 * j4 + 0], h[4 * j4 + 1],
                                      h[4 * j4 + 2], h[4 * j4 + 3]);
        }
        __syncthreads();
#pragma unroll 1
        for (int r = 0; r < 16; ++r) {    // wave wv sweeps rows 16*wv..+15
            int hr = wv * 16 + r;
            const float4* hv = (const float4*)&sH[hr][0];   // wave-uniform
            float a0 = bb, a1 = 0.f, a2 = 0.f, a3 = 0.f;    // 4 indep chains
#pragma unroll
            for (int j4 = 0; j4 < 16; j4 += 4) {
                float4 x0 = hv[j4 + 0], x1 = hv[j4 + 1];
                float4 x2 = hv[j4 + 2], x3 = hv[j4 + 3];
                a0 = fmaf(x0.x, w2r[j4 + 0].x, a0); a0 = fmaf(x0.y, w2r[j4 + 0].y, a0);
                a0 = fmaf(x0.z, w2r[j4 + 0].z, a0); a0 = fmaf(x0.w, w2r[j4 + 0].w, a0);
                a1 = fmaf(x1.x, w2r[j4 + 1].x, a1); a1 = fmaf(x1.y, w2r[j4 + 1].y, a1);
                a1 = fmaf(x1.z, w2r[j4 + 1].z, a1); a1 = fmaf(x1.w, w2r[j4 + 1].w, a1);
                a2 = fmaf(x2.x, w2r[j4 + 2].x, a2); a2 = fmaf(x2.y, w2r[j4 + 2].y, a2);
                a2 = fmaf(x2.z, w2r[j4 + 2].z, a2); a2 = fmaf(x2.w, w2r[j4 + 2].w, a2);
                a3 = fmaf(x3.x, w2r[j4 + 3].x, a3); a3 = fmaf(x3.y, w2r[j4 + 3].y, a3);
                a3 = fmaf(x3.z, w2r[j4 + 3].z, a3); a3 = fmaf(x3.w, w2r[j4 + 3].w, a3);
            }
            // full 256B contiguous row per store instruction
            out[obase + (size_t)(c * 64 + hr) * HID + lane] = (a0 + a1) + (a2 + a3);
        }
        __syncthreads();                  // reads done before next chunk's dump
    }
}

extern "C" void kernel_launch(void* const* d_in, const int* in_sizes, int n_in,
                              void* d_out, int out_size, void* d_ws, size_t ws_size,
                              hipStream_t stream) {
    const int*   seqs     = (const int*)d_in[0];
    const int*   qtok     = (const int*)d_in[1];
    const float* embed    = (const float*)d_in[2];
    const float* W1       = (const float*)d_in[3];
    const float* b1       = (const float*)d_in[4];
    const float* W2       = (const float*)d_in[5];
    const float* b2       = (const float*)d_in[6];
    const float* log_stab = (const float*)d_in[7];
    float* out = (float*)d_out;
    float* ws  = (float*)d_ws;

    int B = in_sizes[1];

    ebb_prep<<<VOCAB, 2 * HID, 0, stream>>>(embed, W1, b1, log_stab, ws);

    int nblk = (B + BLKT - 1) / BLKT;
    ebb_main<<<nblk, BLKT, 0, stream>>>(seqs, qtok, ws, W2, b2, out);
}

// Round 11
// 117.980 us; speedup vs baseline: 1.1768x; 1.0747x over previous
//
#include <hip/hip_runtime.h>

#define VOCAB 64
#define HID 64
#define SEQL 48
#define MSLOTS 8
#define BLKT 256
#define STR 68   // padded table row stride in floats (272B, 16B-aligned)

// ws layout (floats): [0,4096)    Wq = embed @ W1[:, :64].T + b1
//                     [4096,8192) Wm = embed @ W1[:, 64:].T
//                     [8192,8200) ww = w_m / count
__global__ void ebb_prep(const float* __restrict__ embed,
                         const float* __restrict__ W1,
                         const float* __restrict__ b1,
                         const float* __restrict__ log_stab,
                         float* __restrict__ ws) {
    int t = blockIdx.x;            // token 0..63
    int tid = threadIdx.x;         // 0..127
    int table = tid >> 6;          // 0 -> Wq (W1[:, :64]), 1 -> Wm (W1[:, 64:])
    int col = tid & 63;            // output hidden index j
    const float* erow = embed + t * HID;
    const float* wrow = W1 + col * (2 * HID) + table * HID;
    float acc = (table == 0) ? b1[col] : 0.f;   // fold b1 into Wq
#pragma unroll
    for (int k = 0; k < HID; ++k) acc = fmaf(erow[k], wrow[k], acc);
    ws[table * (VOCAB * HID) + t * HID + col] = acc;

    if (blockIdx.x == 0 && tid < MSLOTS) {
        float S = expf(log_stab[0]);
        float cnt = 0.f;
        for (int m = 0; m < MSLOTS; ++m) {
            float age = (float)(MSLOTS - 1 - m);
            cnt += (expf(-age / S) >= 0.05f) ? 1.f : 0.f;
        }
        cnt = fmaxf(cnt, 1.f);
        float age = (float)(MSLOTS - 1 - tid);
        float keep = (expf(-age / S) >= 0.05f) ? 1.f : 0.f;
        float w = expf(-age * (age + 1.f) / (2.f * S)) * keep;
        ws[2 * VOCAB * HID + tid] = w / cnt;
    }
}

// Phase 1: gather tables in LDS, per-thread h[64] in VGPRs (layer 1).
// Phase 2: barrier; every thread dumps h into swizzled sH (unions with the
//          table space -> 64KB total); h regs die, THEN w2r[16] (W2 row for
//          this thread's output column) is loaded into the freed registers.
//          Each wave sweeps its OWN 64 rows (the ones its lanes wrote -> no
//          second barrier) with wave-uniform ds_read_b128 broadcasts of h and
//          resident-W2 FMAs. h[64] and w2r[16] are never co-live -> no spill.
__global__ __launch_bounds__(BLKT, 2)
void ebb_main(const int* __restrict__ seqs, const int* __restrict__ qtok,
              const float* __restrict__ ws, const float* __restrict__ W2,
              const float* __restrict__ b2,
              float* __restrict__ out) {
    __shared__ __align__(16) char smem[65536];
    float (*sWq)[STR] = (float (*)[STR])(smem);           // 17408 B
    float (*sWm)[STR] = (float (*)[STR])(smem + 17408);   // 17408 B
    // phase 2: smem reused as sH: 256 rows x 256 B, XOR-swizzled

    int tid  = threadIdx.x;
    int lane = tid & 63;
    int wv   = tid >> 6;

    // ---- stage gather tables ----
    for (int i = tid; i < VOCAB * HID; i += BLKT) {
        int r = i >> 6, c = i & 63;
        sWq[r][c] = ws[i];
        sWm[r][c] = ws[VOCAB * HID + i];
    }

    // ---- this thread's row inputs ----
    int row = blockIdx.x * BLKT + tid;            // B divisible by 256
    const int* srow = seqs + (size_t)row * SEQL;
    int qt = qtok[row];
    int t0 = srow[39];
    int4 ta = *(const int4*)(srow + 40);
    int4 tb = *(const int4*)(srow + 44);
    int toks[MSLOTS] = {t0, ta.x, ta.y, ta.z, ta.w, tb.x, tb.y, tb.z};
    float bb = b2[lane];

    __syncthreads();   // tables ready

    // ---- layer 1: h = relu(Wq[qt] + sum_m ww[m]*Wm[toks[m]]) ----
    float h[HID];
    {
        const float4* wq = (const float4*)&sWq[qt][0];
#pragma unroll
        for (int j4 = 0; j4 < 16; ++j4) {
            float4 a = wq[j4];
            h[4 * j4 + 0] = a.x; h[4 * j4 + 1] = a.y;
            h[4 * j4 + 2] = a.z; h[4 * j4 + 3] = a.w;
        }
    }
#pragma unroll
    for (int m = 0; m < MSLOTS; ++m) {
        float wwm = ws[2 * VOCAB * HID + m];      // uniform -> s_load
        const float4* wm = (const float4*)&sWm[toks[m]][0];
#pragma unroll
        for (int j4 = 0; j4 < 16; ++j4) {
            float4 a = wm[j4];
            h[4 * j4 + 0] = fmaf(wwm, a.x, h[4 * j4 + 0]);
            h[4 * j4 + 1] = fmaf(wwm, a.y, h[4 * j4 + 1]);
            h[4 * j4 + 2] = fmaf(wwm, a.z, h[4 * j4 + 2]);
            h[4 * j4 + 3] = fmaf(wwm, a.w, h[4 * j4 + 3]);
        }
    }

    __syncthreads();   // all table reads done; safe to overwrite smem as sH

    // ---- dump h (with relu) into swizzled sH; h registers die here ----
    {
        unsigned rbase = (unsigned)tid * 256;
        unsigned sw = ((unsigned)tid & 7u) << 4;
#pragma unroll
        for (int j4 = 0; j4 < 16; ++j4) {
            float4 v = make_float4(fmaxf(h[4 * j4 + 0], 0.f),
                                   fmaxf(h[4 * j4 + 1], 0.f),
                                   fmaxf(h[4 * j4 + 2], 0.f),
                                   fmaxf(h[4 * j4 + 3], 0.f));
            *(float4*)(smem + (rbase + ((unsigned)(j4 * 16) ^ sw))) = v;
        }
    }

    // ---- load resident W2 row into the freed registers ----
    float4 w2r[16];
    {
        const float4* W2v = (const float4*)(W2 + lane * HID);
#pragma unroll
        for (int j4 = 0; j4 < 16; ++j4) w2r[j4] = W2v[j4];
    }

    // ---- sweep this wave's own 64 rows: 2 rows in flight, 4 chains each ----
    // (intra-wave producer/consumer: lgkmcnt ordering suffices, no barrier)
    size_t obase = (size_t)blockIdx.x * BLKT + (size_t)wv * 64;
#pragma unroll 1
    for (int r = 0; r < 64; r += 2) {
        int hr0 = wv * 64 + r, hr1 = hr0 + 1;
        const char* p0 = smem + hr0 * 256;
        const char* p1 = smem + hr1 * 256;
        unsigned x0 = ((unsigned)hr0 & 7u) << 4;
        unsigned x1 = ((unsigned)hr1 & 7u) << 4;
        float a0 = bb, a1 = 0.f, a2 = 0.f, a3 = 0.f;
        float c0 = bb, c1 = 0.f, c2 = 0.f, c3 = 0.f;
#pragma unroll
        for (int j4 = 0; j4 < 16; j4 += 4) {
            float4 u0 = *(const float4*)(p0 + (((unsigned)((j4 + 0) * 16)) ^ x0));
            float4 u1 = *(const float4*)(p0 + (((unsigned)((j4 + 1) * 16)) ^ x0));
            float4 u2 = *(const float4*)(p0 + (((unsigned)((j4 + 2) * 16)) ^ x0));
            float4 u3 = *(const float4*)(p0 + (((unsigned)((j4 + 3) * 16)) ^ x0));
            float4 v0 = *(const float4*)(p1 + (((unsigned)((j4 + 0) * 16)) ^ x1));
            float4 v1 = *(const float4*)(p1 + (((unsigned)((j4 + 1) * 16)) ^ x1));
            float4 v2 = *(const float4*)(p1 + (((unsigned)((j4 + 2) * 16)) ^ x1));
            float4 v3 = *(const float4*)(p1 + (((unsigned)((j4 + 3) * 16)) ^ x1));
            a0 = fmaf(u0.x, w2r[j4 + 0].x, a0); a0 = fmaf(u0.y, w2r[j4 + 0].y, a0);
            a0 = fmaf(u0.z, w2r[j4 + 0].z, a0); a0 = fmaf(u0.w, w2r[j4 + 0].w, a0);
            a1 = fmaf(u1.x, w2r[j4 + 1].x, a1); a1 = fmaf(u1.y, w2r[j4 + 1].y, a1);
            a1 = fmaf(u1.z, w2r[j4 + 1].z, a1); a1 = fmaf(u1.w, w2r[j4 + 1].w, a1);
            a2 = fmaf(u2.x, w2r[j4 + 2].x, a2); a2 = fmaf(u2.y, w2r[j4 + 2].y, a2);
            a2 = fmaf(u2.z, w2r[j4 + 2].z, a2); a2 = fmaf(u2.w, w2r[j4 + 2].w, a2);
            a3 = fmaf(u3.x, w2r[j4 + 3].x, a3); a3 = fmaf(u3.y, w2r[j4 + 3].y, a3);
            a3 = fmaf(u3.z, w2r[j4 + 3].z, a3); a3 = fmaf(u3.w, w2r[j4 + 3].w, a3);
            c0 = fmaf(v0.x, w2r[j4 + 0].x, c0); c0 = fmaf(v0.y, w2r[j4 + 0].y, c0);
            c0 = fmaf(v0.z, w2r[j4 + 0].z, c0); c0 = fmaf(v0.w, w2r[j4 + 0].w, c0);
            c1 = fmaf(v1.x, w2r[j4 + 1].x, c1); c1 = fmaf(v1.y, w2r[j4 + 1].y, c1);
            c1 = fmaf(v1.z, w2r[j4 + 1].z, c1); c1 = fmaf(v1.w, w2r[j4 + 1].w, c1);
            c2 = fmaf(v2.x, w2r[j4 + 2].x, c2); c2 = fmaf(v2.y, w2r[j4 + 2].y, c2);
            c2 = fmaf(v2.z, w2r[j4 + 2].z, c2); c2 = fmaf(v2.w, w2r[j4 + 2].w, c2);
            c3 = fmaf(v3.x, w2r[j4 + 3].x, c3); c3 = fmaf(v3.y, w2r[j4 + 3].y, c3);
            c3 = fmaf(v3.z, w2r[j4 + 3].z, c3); c3 = fmaf(v3.w, w2r[j4 + 3].w, c3);
        }
        // full 256B contiguous row per store instruction
        out[(obase + r) * HID + lane]     = (a0 + a1) + (a2 + a3);
        out[(obase + r + 1) * HID + lane] = (c0 + c1) + (c2 + c3);
    }
}

extern "C" void kernel_launch(void* const* d_in, const int* in_sizes, int n_in,
                              void* d_out, int out_size, void* d_ws, size_t ws_size,
                              hipStream_t stream) {
    const int*   seqs     = (const int*)d_in[0];
    const int*   qtok     = (const int*)d_in[1];
    const float* embed    = (const float*)d_in[2];
    const float* W1       = (const float*)d_in[3];
    const float* b1       = (const float*)d_in[4];
    const float* W2       = (const float*)d_in[5];
    const float* b2       = (const float*)d_in[6];
    const float* log_stab = (const float*)d_in[7];
    float* out = (float*)d_out;
    float* ws  = (float*)d_ws;

    int B = in_sizes[1];

    ebb_prep<<<VOCAB, 2 * HID, 0, stream>>>(embed, W1, b1, log_stab, ws);

    int nblk = (B + BLKT - 1) / BLKT;
    ebb_main<<<nblk, BLKT, 0, stream>>>(seqs, qtok, ws, W2, b2, out);
}

// Round 12
// 102.755 us; speedup vs baseline: 1.3512x; 1.1482x over previous
//
#include <hip/hip_runtime.h>

#define VOCAB 64
#define HID 64
#define SEQL 48
#define MSLOTS 8
#define BLKT 256
#define STR 68   // padded table row stride in floats (272B, 16B-aligned)

typedef __attribute__((ext_vector_type(8))) short bf16x8;
typedef __attribute__((ext_vector_type(4))) float f32x4;

__device__ __forceinline__ unsigned bf16_rne(float x) {
    unsigned u = __float_as_uint(x);
    return (u + 0x7FFFu + ((u >> 16) & 1u)) >> 16;
}
__device__ __forceinline__ float bf16f(unsigned b) {
    return __uint_as_float(b << 16);
}

// ws layout (floats): [0,4096)    Wq = embed @ W1[:, :64].T + b1
//                     [4096,8192) Wm = embed @ W1[:, 64:].T
//                     [8192,8200) ww = w_m / count
__global__ void ebb_prep(const float* __restrict__ embed,
                         const float* __restrict__ W1,
                         const float* __restrict__ b1,
                         const float* __restrict__ log_stab,
                         float* __restrict__ ws) {
    int t = blockIdx.x;
    int tid = threadIdx.x;
    int table = tid >> 6;
    int col = tid & 63;
    const float* erow = embed + t * HID;
    const float* wrow = W1 + col * (2 * HID) + table * HID;
    float acc = (table == 0) ? b1[col] : 0.f;
#pragma unroll
    for (int k = 0; k < HID; ++k) acc = fmaf(erow[k], wrow[k], acc);
    ws[table * (VOCAB * HID) + t * HID + col] = acc;

    if (blockIdx.x == 0 && tid < MSLOTS) {
        float S = expf(log_stab[0]);
        float cnt = 0.f;
        for (int m = 0; m < MSLOTS; ++m) {
            float age = (float)(MSLOTS - 1 - m);
            cnt += (expf(-age / S) >= 0.05f) ? 1.f : 0.f;
        }
        cnt = fmaxf(cnt, 1.f);
        float age = (float)(MSLOTS - 1 - tid);
        float keep = (expf(-age / S) >= 0.05f) ? 1.f : 0.f;
        float w = expf(-age * (age + 1.f) / (2.f * S)) * keep;
        ws[2 * VOCAB * HID + tid] = w / cnt;
    }
}

// Phase 1: gather tables in LDS (34.8KB), per-thread h[64] f32 (layer 1).
// Phase 2: barrier; relu(h) split into bf16 hi/lo and dumped into the SAME
//          smem (union, 64KB: H_hi[256][64]bf16 @0, H_lo @32768), XOR-swizzled
//          (byte ^= (row&7)<<4) so the per-lane stride-128B A-fragment reads
//          don't bank-conflict. Layer 2 = MFMA 16x16x32_bf16, 3 passes
//          (hh+hl+lh ~ f32 precision). Each wave computes its own 64 rows
//          (rows its lanes wrote -> intra-wave lgkmcnt, no barrier).
//          A/B operand pattern = m97's ref-checked gemm_bt layout:
//          A=[M][K] rowmajor, B^T=W2=[N][K] rowmajor, lane holds 8 contig k;
//          C: col=lane&15, row=(lane>>4)*4+reg.
__global__ __launch_bounds__(BLKT, 2)
void ebb_main(const int* __restrict__ seqs, const int* __restrict__ qtok,
              const float* __restrict__ ws, const float* __restrict__ W2,
              const float* __restrict__ b2,
              float* __restrict__ out) {
    __shared__ __align__(16) char smem[65536];
    float (*sWq)[STR] = (float (*)[STR])(smem);           // 17408 B
    float (*sWm)[STR] = (float (*)[STR])(smem + 17408);   // 17408 B

    int tid  = threadIdx.x;
    int lane = tid & 63;
    int wv   = tid >> 6;

    // ---- stage gather tables ----
    for (int i = tid; i < VOCAB * HID; i += BLKT) {
        int r = i >> 6, c = i & 63;
        sWq[r][c] = ws[i];
        sWm[r][c] = ws[VOCAB * HID + i];
    }

    // ---- this thread's row inputs ----
    int row = blockIdx.x * BLKT + tid;            // B divisible by 256
    const int* srow = seqs + (size_t)row * SEQL;
    int qt = qtok[row];
    int t0 = srow[39];
    int4 ta = *(const int4*)(srow + 40);
    int4 tb = *(const int4*)(srow + 44);
    int toks[MSLOTS] = {t0, ta.x, ta.y, ta.z, ta.w, tb.x, tb.y, tb.z};

    __syncthreads();   // tables ready

    // ---- layer 1: h = Wq[qt] + sum_m ww[m]*Wm[toks[m]]  (b1 folded) ----
    float h[HID];
    {
        const float4* wq = (const float4*)&sWq[qt][0];
#pragma unroll
        for (int j4 = 0; j4 < 16; ++j4) {
            float4 a = wq[j4];
            h[4 * j4 + 0] = a.x; h[4 * j4 + 1] = a.y;
            h[4 * j4 + 2] = a.z; h[4 * j4 + 3] = a.w;
        }
    }
#pragma unroll
    for (int m = 0; m < MSLOTS; ++m) {
        float wwm = ws[2 * VOCAB * HID + m];      // uniform -> s_load
        const float4* wm = (const float4*)&sWm[toks[m]][0];
#pragma unroll
        for (int j4 = 0; j4 < 16; ++j4) {
            float4 a = wm[j4];
            h[4 * j4 + 0] = fmaf(wwm, a.x, h[4 * j4 + 0]);
            h[4 * j4 + 1] = fmaf(wwm, a.y, h[4 * j4 + 1]);
            h[4 * j4 + 2] = fmaf(wwm, a.z, h[4 * j4 + 2]);
            h[4 * j4 + 3] = fmaf(wwm, a.w, h[4 * j4 + 3]);
        }
    }

    __syncthreads();   // all table reads done; smem becomes H_hi/H_lo

    // ---- relu + split-bf16 + swizzled dump; h registers die here ----
    {
        unsigned rbase = (unsigned)tid * 128;          // 64 bf16 = 128B/row
        unsigned sw = ((unsigned)tid & 7u) << 4;
#pragma unroll
        for (int c8 = 0; c8 < 8; ++c8) {               // 8 chunks x 8 elems
            unsigned off = ((unsigned)(c8 * 16)) ^ sw;
            int hw[4], lw[4];
#pragma unroll
            for (int p = 0; p < 4; ++p) {
                float v0 = fmaxf(h[c8 * 8 + 2 * p + 0], 0.f);
                float v1 = fmaxf(h[c8 * 8 + 2 * p + 1], 0.f);
                unsigned h0 = bf16_rne(v0), h1 = bf16_rne(v1);
                unsigned l0 = bf16_rne(v0 - bf16f(h0));
                unsigned l1 = bf16_rne(v1 - bf16f(h1));
                hw[p] = (int)(h0 | (h1 << 16));
                lw[p] = (int)(l0 | (l1 << 16));
            }
            *(int4*)(smem + (rbase + off))         = make_int4(hw[0], hw[1], hw[2], hw[3]);
            *(int4*)(smem + 32768 + (rbase + off)) = make_int4(lw[0], lw[1], lw[2], lw[3]);
        }
    }
    __builtin_amdgcn_sched_barrier(0);   // keep W2 frag loads AFTER h dies

    // ---- B-operand fragments from W2 (global, L2/L3-hot): 4 Ntiles x 2 K ----
    bf16x8 wbh[8], wbl[8];               // idx = nt*2 + kt  (64 VGPRs)
    {
        int n  = lane & 15;
        int kg = (lane >> 4) * 8;
#pragma unroll
        for (int nt = 0; nt < 4; ++nt) {
            const float* wr = W2 + (size_t)(nt * 16 + n) * HID + kg;
#pragma unroll
            for (int kt = 0; kt < 2; ++kt) {
                float4 p0 = *(const float4*)(wr + kt * 32);
                float4 p1 = *(const float4*)(wr + kt * 32 + 4);
                float vv[8] = {p0.x, p0.y, p0.z, p0.w, p1.x, p1.y, p1.z, p1.w};
                bf16x8 bh, bl;
#pragma unroll
                for (int i = 0; i < 8; ++i) {
                    unsigned hb = bf16_rne(vv[i]);
                    bh[i] = (short)hb;
                    bl[i] = (short)bf16_rne(vv[i] - bf16f(hb));
                }
                wbh[nt * 2 + kt] = bh;
                wbl[nt * 2 + kt] = bl;
            }
        }
    }
    float bcol[4];
#pragma unroll
    for (int nt = 0; nt < 4; ++nt) bcol[nt] = b2[nt * 16 + (lane & 15)];

    // ---- MFMA sweep: this wave's 4 M-tiles (its own 64 rows) ----
#pragma unroll 1
    for (int mt = 0; mt < 4; ++mt) {
        int r0 = wv * 64 + mt * 16;
        unsigned arow  = (unsigned)(r0 + (lane & 15));
        unsigned abase = arow * 128;
        unsigned asw   = (arow & 7u) << 4;
        bf16x8 ah[2], al[2];
#pragma unroll
        for (int kt = 0; kt < 2; ++kt) {
            unsigned off = ((unsigned)(((lane >> 4) + 4 * kt) * 16)) ^ asw;
            ah[kt] = *(const bf16x8*)(smem + (abase + off));
            al[kt] = *(const bf16x8*)(smem + 32768 + (abase + off));
        }
#pragma unroll
        for (int nt = 0; nt < 4; ++nt) {
            f32x4 acc = {bcol[nt], bcol[nt], bcol[nt], bcol[nt]};
#pragma unroll
            for (int kt = 0; kt < 2; ++kt) {
                acc = __builtin_amdgcn_mfma_f32_16x16x32_bf16(ah[kt], wbh[nt * 2 + kt], acc, 0, 0, 0);
                acc = __builtin_amdgcn_mfma_f32_16x16x32_bf16(ah[kt], wbl[nt * 2 + kt], acc, 0, 0, 0);
                acc = __builtin_amdgcn_mfma_f32_16x16x32_bf16(al[kt], wbh[nt * 2 + kt], acc, 0, 0, 0);
            }
            // C: col = nt*16 + (lane&15), row = r0 + (lane>>4)*4 + reg
            size_t ob = ((size_t)blockIdx.x * BLKT + (size_t)(r0 + (lane >> 4) * 4)) * HID
                        + (size_t)(nt * 16 + (lane & 15));
            out[ob + 0 * HID] = acc[0];
            out[ob + 1 * HID] = acc[1];
            out[ob + 2 * HID] = acc[2];
            out[ob + 3 * HID] = acc[3];
        }
    }
}

extern "C" void kernel_launch(void* const* d_in, const int* in_sizes, int n_in,
                              void* d_out, int out_size, void* d_ws, size_t ws_size,
                              hipStream_t stream) {
    const int*   seqs     = (const int*)d_in[0];
    const int*   qtok     = (const int*)d_in[1];
    const float* embed    = (const float*)d_in[2];
    const float* W1       = (const float*)d_in[3];
    const float* b1       = (const float*)d_in[4];
    const float* W2       = (const float*)d_in[5];
    const float* b2       = (const float*)d_in[6];
    const float* log_stab = (const float*)d_in[7];
    float* out = (float*)d_out;
    float* ws  = (float*)d_ws;

    int B = in_sizes[1];

    ebb_prep<<<VOCAB, 2 * HID, 0, stream>>>(embed, W1, b1, log_stab, ws);

    int nblk = (B + BLKT - 1) / BLKT;
    ebb_main<<<nblk, BLKT, 0, stream>>>(seqs, qtok, ws, W2, b2, out);
}